// Round 6
// baseline (410.588 us; speedup 1.0000x reference)
//
#include <hip/hip_runtime.h>
#include <hip/hip_bf16.h>
#include <hip/hip_fp16.h>

// GraphSAGE 3-layer + pool + linear.
// R6: GEMM stages B-fragment tables in LDS (64 KB) once per source per block;
// 4-wave blocks, 192-node tiles (261 blocks, all co-resident). K-loop reads B
// via conflict-free ds_read_b128; A direct from global (line-tiled frags).
// agg gathers fp16 mirror (256 B/edge); GEMM uses split-bf16 packed (hi|lo u32):
// C = Ahi*Bhi + Ahi*Blo + Alo*Bhi (drops lo*lo ~2^-18). pool+final fused.

#define FH 128
#define OUTD 256
#define SCHUNK 2048

typedef unsigned int u32;
typedef unsigned short u16;
typedef __attribute__((ext_vector_type(8))) short bf8frag;
typedef __attribute__((ext_vector_type(4))) float f4frag;

__device__ inline u32 pack_bf16pair(float v) {
    u32 b = __float_as_uint(v);
    u32 hb = (b + 0x7FFFu + ((b >> 16) & 1u)) & 0xFFFF0000u;
    float rem = v - __uint_as_float(hb);
    u32 rb = __float_as_uint(rem);
    u32 lb = ((rb + 0x7FFFu + ((rb >> 16) & 1u)) >> 16) & 0xFFFFu;
    return hb | lb;
}
__device__ inline float unpack_f(u32 u) {
    return __uint_as_float(u & 0xFFFF0000u) + __uint_as_float(u << 16);
}

// ---------------------------------------------------------------- histogram
__global__ void hist_kernel(const int* __restrict__ dst, int* __restrict__ cnt, int E) {
    int e = blockIdx.x * 256 + threadIdx.x;
    if (e < E) atomicAdd(&cnt[dst[e]], 1);
}

// ---------------------------------------------- scan pass A: per-block sums
__global__ void scanA_kernel(const int* __restrict__ cnt, int* __restrict__ bsum, int n) {
    __shared__ int ws[4];
    int b = blockIdx.x, t = threadIdx.x;
    int base = b * SCHUNK + t * 8;
    int s = 0;
    #pragma unroll
    for (int k = 0; k < 8; ++k) {
        int i = base + k;
        s += (i < n) ? cnt[i] : 0;
    }
    #pragma unroll
    for (int off = 32; off >= 1; off >>= 1) s += __shfl_xor(s, off, 64);
    int w = t >> 6, lane = t & 63;
    if (lane == 0) ws[w] = s;
    __syncthreads();
    if (t == 0) bsum[b] = ws[0] + ws[1] + ws[2] + ws[3];
}

// ------------------------------- scan pass B: scan block sums (1 wave)
__global__ void scanB_kernel(const int* __restrict__ bsum, int* __restrict__ boff,
                             int* __restrict__ rp, int B, int n) {
    int t = threadIdx.x;  // 64 threads
    int v = (t < B) ? bsum[t] : 0;
    int x = v;
    #pragma unroll
    for (int off = 1; off < 64; off <<= 1) {
        int y = __shfl_up(x, off, 64);
        if (t >= off) x += y;
    }
    if (t < B) boff[t] = x - v;
    if (t == 63) rp[n] = x;
}

// --------------------------- scan pass C: full exclusive scan + emit rp/dinv
__global__ void scanC_kernel(const int* __restrict__ cnt, const int* __restrict__ boff,
                             int* __restrict__ rp, float* __restrict__ dinv, int n) {
    __shared__ int ws[4];
    int b = blockIdx.x, t = threadIdx.x;
    int base = b * SCHUNK + t * 8;
    int v[8];
    int ts = 0;
    #pragma unroll
    for (int k = 0; k < 8; ++k) {
        int i = base + k;
        v[k] = (i < n) ? cnt[i] : 0;
        ts += v[k];
    }
    int w = t >> 6, lane = t & 63;
    int x = ts;
    #pragma unroll
    for (int off = 1; off < 64; off <<= 1) {
        int y = __shfl_up(x, off, 64);
        if (lane >= off) x += y;
    }
    if (lane == 63) ws[w] = x;
    __syncthreads();
    int woff = 0;
    #pragma unroll
    for (int q = 0; q < 4; ++q) woff += (q < w) ? ws[q] : 0;
    int run = boff[b] + woff + (x - ts);
    #pragma unroll
    for (int k = 0; k < 8; ++k) {
        int i = base + k;
        if (i < n) {
            rp[i] = run;
            dinv[i] = 1.0f / (float)max(v[k], 1);
        }
        run += v[k];
    }
}

// --------------------------------------------------------- CSR edge scatter
__global__ void scatter_kernel(const int* __restrict__ src, const int* __restrict__ dst,
                               const int* __restrict__ rp, int* __restrict__ cursor,
                               int* __restrict__ esrc, int E) {
    int e = blockIdx.x * 256 + threadIdx.x;
    if (e < E) {
        int d = dst[e];
        int pos = rp[d] + atomicAdd(&cursor[d], 1);
        esrc[pos] = src[e];
    }
}

// ------------------------------------------------------- graph range bounds
__global__ void graph_bounds_kernel(const int* __restrict__ batch, int* __restrict__ gstart,
                                    int n, int g) {
    int i = blockIdx.x * 256 + threadIdx.x;
    if (i >= n) return;
    int b = batch[i];
    int pb = (i == 0) ? -1 : batch[i - 1];
    for (int q = pb + 1; q <= b; ++q) gstart[q] = i;
    if (i == n - 1) {
        for (int q = b + 1; q <= g; ++q) gstart[q] = n;
    }
}

// --------------------------------- prep: x -> packed bf16-pair + fp16 mirror
__global__ void prep_x(const float* __restrict__ x, u32* __restrict__ hP,
                       u16* __restrict__ x16, int n4) {
    int id = blockIdx.x * 256 + threadIdx.x;
    if (id >= n4) return;
    float4 v = *(const float4*)(x + (size_t)id * 4);
    uint4 o = {pack_bf16pair(v.x), pack_bf16pair(v.y), pack_bf16pair(v.z), pack_bf16pair(v.w)};
    *(uint4*)(hP + (size_t)id * 4) = o;
    __half h0 = __float2half(v.x), h1 = __float2half(v.y);
    __half h2 = __float2half(v.z), h3 = __float2half(v.w);
    ushort4 s;
    s.x = *(u16*)&h0; s.y = *(u16*)&h1; s.z = *(u16*)&h2; s.w = *(u16*)&h3;
    *(ushort4*)(x16 + (size_t)id * 4) = s;
}

// --------------------- prep: weights -> B fragments in MFMA operand order
// Per array: Bf[(ks*8 + ot)*64 + lane], lane l holds
// W[out=ot*16+(l&15)][k = (ks&3)*32 + (l>>4)*8 + i], i=0..7.
// ks 0-3: hi part, ks 4-7: lo part.
__global__ void prep_w(const float* __restrict__ W0, const float* __restrict__ W1,
                       const float* __restrict__ W2, const float* __restrict__ W3,
                       const float* __restrict__ W4, const float* __restrict__ W5,
                       uint4* __restrict__ Bf) {
    const float* Ws[6] = {W0, W1, W2, W3, W4, W5};
    int ks = blockIdx.x;      // 0..7
    int arr = blockIdx.y;     // 0..5
    int l = threadIdx.x;      // 0..63
    const float* W = Ws[arr];
    bool use_lo = (ks >= 4);
    int kb = (ks & 3) * 32 + (l >> 4) * 8;
    uint4* out = Bf + (size_t)arr * 4096;
    #pragma unroll
    for (int ot = 0; ot < 8; ++ot) {
        int o = ot * 16 + (l & 15);
        u32 h[8];
        #pragma unroll
        for (int i = 0; i < 8; ++i) {
            float v = W[o * 128 + kb + i];
            u32 b = __float_as_uint(v);
            u32 hb = (b + 0x7FFFu + ((b >> 16) & 1u)) & 0xFFFF0000u;
            if (use_lo) {
                float rem = v - __uint_as_float(hb);
                u32 rb = __float_as_uint(rem);
                h[i] = ((rb + 0x7FFFu + ((rb >> 16) & 1u)) >> 16) & 0xFFFFu;
            } else {
                h[i] = hb >> 16;
            }
        }
        uint4 u;
        u.x = h[0] | (h[1] << 16);
        u.y = h[2] | (h[3] << 16);
        u.z = h[4] | (h[5] << 16);
        u.w = h[6] | (h[7] << 16);
        out[(ks * 8 + ot) * 64 + l] = u;
    }
}

// --------------------------------------------------- mean aggregation (CSR)
// 16 lanes per node; lane covers 8 fp16 features (uint4 = 16B); x4 edge unroll.
__device__ inline void add8(float* a, uint4 u) {
    float2 f0 = __half22float2(*(__half2*)&u.x);
    float2 f1 = __half22float2(*(__half2*)&u.y);
    float2 f2 = __half22float2(*(__half2*)&u.z);
    float2 f3 = __half22float2(*(__half2*)&u.w);
    a[0] += f0.x; a[1] += f0.y; a[2] += f1.x; a[3] += f1.y;
    a[4] += f2.x; a[5] += f2.y; a[6] += f3.x; a[7] += f3.y;
}

__global__ void agg_kernel(const u16* __restrict__ h16,
                           const int* __restrict__ rp, const int* __restrict__ esrc,
                           const float* __restrict__ dinv,
                           u32* __restrict__ aggP, int n_nodes) {
    int node = blockIdx.x * 16 + (threadIdx.x >> 4);
    if (node >= n_nodes) return;
    int lane = threadIdx.x & 15;
    int f = lane * 8;
    int s0 = rp[node], s1 = rp[node + 1];
    float a0[8] = {0, 0, 0, 0, 0, 0, 0, 0};
    float a1[8] = {0, 0, 0, 0, 0, 0, 0, 0};
    float a2[8] = {0, 0, 0, 0, 0, 0, 0, 0};
    float a3[8] = {0, 0, 0, 0, 0, 0, 0, 0};
    int j = s0;
    for (; j + 4 <= s1; j += 4) {
        int i0 = esrc[j], i1 = esrc[j + 1], i2 = esrc[j + 2], i3 = esrc[j + 3];
        uint4 u0 = *(const uint4*)(h16 + (size_t)i0 * FH + f);
        uint4 u1 = *(const uint4*)(h16 + (size_t)i1 * FH + f);
        uint4 u2 = *(const uint4*)(h16 + (size_t)i2 * FH + f);
        uint4 u3 = *(const uint4*)(h16 + (size_t)i3 * FH + f);
        add8(a0, u0); add8(a1, u1); add8(a2, u2); add8(a3, u3);
    }
    for (; j < s1; ++j) {
        uint4 u0 = *(const uint4*)(h16 + (size_t)esrc[j] * FH + f);
        add8(a0, u0);
    }
    float di = dinv[node];
    u32 o[8];
    #pragma unroll
    for (int i = 0; i < 8; ++i)
        o[i] = pack_bf16pair((a0[i] + a1[i] + a2[i] + a3[i]) * di);
    uint4 w0 = {o[0], o[1], o[2], o[3]};
    uint4 w1 = {o[4], o[5], o[6], o[7]};
    *(uint4*)(aggP + (size_t)node * FH + f) = w0;
    *(uint4*)(aggP + (size_t)node * FH + f + 4) = w1;
}

// ----------------------------------------------------------- MFMA SAGE GEMM
// 256 threads (4 waves). Tile 192 nodes x 128 outs; wave w: nodes w*48..w*48+47.
// Per source: stage full B table (hi+lo, 64 KB) into LDS cooperatively, one
// barrier, then K-loop with ds_read_b128 B-frags + global A-frags (24 KB/wave).
// acc[3][8] per wave. Split-bf16: Ahi*Bhi + Ahi*Blo + Alo*Bhi.
__global__ __launch_bounds__(256, 2)
void mfma_gemm(const u32* __restrict__ A1, const u32* __restrict__ A2,
               const uint4* __restrict__ Bf1, const uint4* __restrict__ Bf2,
               const float* __restrict__ bias, u32* __restrict__ outP,
               u16* __restrict__ out16, int do_relu) {
    __shared__ uint4 Bl[4096];  // 64 KB: [ks 0..7][ot 0..7][lane 0..63]
    int tid = threadIdx.x;
    int l = tid & 63;
    int wv = tid >> 6;
    int bn0 = blockIdx.x * 192 + wv * 48;
    int m = l & 15, q = l >> 4;  // q in 0..3

    f4frag acc[3][8];
    #pragma unroll
    for (int i = 0; i < 3; ++i)
        #pragma unroll
        for (int o = 0; o < 8; ++o)
            acc[i][o] = (f4frag){0.f, 0.f, 0.f, 0.f};

    #pragma unroll
    for (int p = 0; p < 2; ++p) {
        const u32* P = p ? A2 : A1;
        const uint4* Bf = p ? Bf2 : Bf1;

        // ---- stage B table for this source ----
        __syncthreads();   // all waves done with previous source's B
        #pragma unroll
        for (int u = 0; u < 16; ++u)
            Bl[u * 256 + tid] = Bf[u * 256 + tid];
        __syncthreads();

        #pragma unroll
        for (int s = 0; s < 4; ++s) {
            // ---- A frags for this k-slice (global, line-tiled) ----
            bf8frag Ahi[3], Alo[3];
            #pragma unroll
            for (int nt = 0; nt < 3; ++nt) {
                const u32* ap = P + (size_t)(bn0 + nt * 16 + m) * FH + q * 8 + s * 32;
                uint4 p0 = *(const uint4*)(ap);
                uint4 p1 = *(const uint4*)(ap + 4);
                uint4 h, lo;
                h.x = (p0.x >> 16) | (p0.y & 0xFFFF0000u);
                h.y = (p0.z >> 16) | (p0.w & 0xFFFF0000u);
                h.z = (p1.x >> 16) | (p1.y & 0xFFFF0000u);
                h.w = (p1.z >> 16) | (p1.w & 0xFFFF0000u);
                lo.x = (p0.x & 0xFFFFu) | (p0.y << 16);
                lo.y = (p0.z & 0xFFFFu) | (p0.w << 16);
                lo.z = (p1.x & 0xFFFFu) | (p1.y << 16);
                lo.w = (p1.z & 0xFFFFu) | (p1.w << 16);
                Ahi[nt] = *(bf8frag*)&h;
                Alo[nt] = *(bf8frag*)&lo;
            }
            // ---- B frags from LDS (conflict-free b128) ----
            bf8frag Bhi[8], Blo[8];
            #pragma unroll
            for (int ot = 0; ot < 8; ++ot) {
                Bhi[ot] = *(const bf8frag*)&Bl[(size_t)((s)     * 8 + ot) * 64 + l];
                Blo[ot] = *(const bf8frag*)&Bl[(size_t)((s + 4) * 8 + ot) * 64 + l];
            }
            // ---- 72 MFMAs, 24 independent acc chains ----
            #pragma unroll
            for (int ot = 0; ot < 8; ++ot)
                #pragma unroll
                for (int nt = 0; nt < 3; ++nt)
                    acc[nt][ot] = __builtin_amdgcn_mfma_f32_16x16x32_bf16(Ahi[nt], Bhi[ot], acc[nt][ot], 0, 0, 0);
            #pragma unroll
            for (int ot = 0; ot < 8; ++ot)
                #pragma unroll
                for (int nt = 0; nt < 3; ++nt)
                    acc[nt][ot] = __builtin_amdgcn_mfma_f32_16x16x32_bf16(Ahi[nt], Blo[ot], acc[nt][ot], 0, 0, 0);
            #pragma unroll
            for (int ot = 0; ot < 8; ++ot)
                #pragma unroll
                for (int nt = 0; nt < 3; ++nt)
                    acc[nt][ot] = __builtin_amdgcn_mfma_f32_16x16x32_bf16(Alo[nt], Bhi[ot], acc[nt][ot], 0, 0, 0);
        }
    }

    // ---- epilogue: bias (+relu), pack, store (D: col=l&15, row=q*4+r) ----
    float vout[3][4][8];
    #pragma unroll
    for (int nt = 0; nt < 3; ++nt)
        #pragma unroll
        for (int r = 0; r < 4; ++r)
            #pragma unroll
            for (int ot = 0; ot < 8; ++ot) {
                float v = acc[nt][ot][r] + bias[ot * 16 + m];
                if (do_relu) v = fmaxf(v, 0.f);
                vout[nt][r][ot] = v;
            }
    #pragma unroll
    for (int nt = 0; nt < 3; ++nt)
        #pragma unroll
        for (int r = 0; r < 4; ++r) {
            int node = bn0 + nt * 16 + q * 4 + r;
            #pragma unroll
            for (int ot = 0; ot < 8; ++ot)
                outP[(size_t)node * FH + ot * 16 + m] = pack_bf16pair(vout[nt][r][ot]);
        }
    if (out16) {
        #pragma unroll
        for (int nt = 0; nt < 3; ++nt)
            #pragma unroll
            for (int r = 0; r < 4; ++r) {
                int node = bn0 + nt * 16 + q * 4 + r;
                #pragma unroll
                for (int ot = 0; ot < 8; ++ot) {
                    __half h = __float2half(vout[nt][r][ot]);
                    out16[(size_t)node * FH + ot * 16 + m] = *(u16*)&h;
                }
            }
    }
}

// --------------------------------------------- fused pooling + final linear
// 128 threads per graph: single pass computes max+mean into LDS, then each
// thread does 2 output dots (256-wide GEMV vs Wlin).
__global__ void pool_final(const u32* __restrict__ hP, const int* __restrict__ gstart,
                           const float* __restrict__ Wlin, const float* __restrict__ blin,
                           float* __restrict__ out) {
    __shared__ float pr[2 * FH];
    int g = blockIdx.x;
    int f = threadIdx.x;  // 128
    int s = gstart[g], e = gstart[g + 1];
    float mx = -INFINITY, sum = 0.f;
    for (int n = s; n < e; ++n) {
        float v = unpack_f(hP[(size_t)n * FH + f]);
        mx = fmaxf(mx, v);
        sum += v;
    }
    int c = e - s;
    pr[f] = (c > 0) ? mx : 0.f;
    pr[FH + f] = sum / (float)max(c, 1);
    __syncthreads();
    #pragma unroll
    for (int h2 = 0; h2 < 2; ++h2) {
        int o = h2 * FH + f;
        const float4* wr = (const float4*)(Wlin + (size_t)o * (2 * FH));
        float acc = 0.f;
        #pragma unroll
        for (int j = 0; j < (2 * FH) / 4; ++j) {
            float4 wv = wr[j];
            acc += wv.x * pr[j * 4 + 0] + wv.y * pr[j * 4 + 1] +
                   wv.z * pr[j * 4 + 2] + wv.w * pr[j * 4 + 3];
        }
        out[(size_t)g * OUTD + o] = acc + blin[o];
    }
}

extern "C" void kernel_launch(void* const* d_in, const int* in_sizes, int n_in,
                              void* d_out, int out_size, void* d_ws, size_t ws_size,
                              hipStream_t stream) {
    const float* x     = (const float*)d_in[0];
    const int*   ei    = (const int*)d_in[1];
    const int*   batch = (const int*)d_in[2];
    const float* W1l = (const float*)d_in[3];
    const float* b1  = (const float*)d_in[4];
    const float* W1r = (const float*)d_in[5];
    const float* W2l = (const float*)d_in[6];
    const float* b2  = (const float*)d_in[7];
    const float* W2r = (const float*)d_in[8];
    const float* W3l = (const float*)d_in[9];
    const float* b3  = (const float*)d_in[10];
    const float* W3r = (const float*)d_in[11];
    const float* Wlin = (const float*)d_in[12];
    const float* blin = (const float*)d_in[13];
    float* out = (float*)d_out;

    const int E = in_sizes[1] / 2;
    const int N = in_sizes[2];
    const int G = out_size / OUTD;
    const int* src = ei;
    const int* dst = ei + E;
    const int NB = (N + SCHUNK - 1) / SCHUNK;
    const int GB = (N + 191) / 192;   // gemm blocks (192-node tiles)
    const int NP = GB * 192;          // padded node count

    // ---- workspace carve-up ----
    char* w = (char*)d_ws;
    auto alloc = [&](size_t bytes) {
        void* p = (void*)w;
        w += (bytes + 255) & ~(size_t)255;
        return p;
    };
    int*   cnt    = (int*)alloc((size_t)2 * N * sizeof(int));
    int*   cursor = cnt + N;
    int*   rp     = (int*)alloc((size_t)(N + 1) * sizeof(int));
    int*   esrc   = (int*)alloc((size_t)E * sizeof(int));
    int*   gstart = (int*)alloc((size_t)(G + 1) * sizeof(int));
    float* dinv   = (float*)alloc((size_t)N * sizeof(float));
    int*   bsum   = (int*)alloc(64 * sizeof(int));
    int*   boff   = (int*)alloc(64 * sizeof(int));
    u32*   aggP   = (u32*)alloc((size_t)NP * FH * sizeof(u32));
    u32*   hPa    = (u32*)alloc((size_t)NP * FH * sizeof(u32));
    u32*   hPb    = (u32*)alloc((size_t)NP * FH * sizeof(u32));
    u16*   F16A   = (u16*)alloc((size_t)NP * FH * sizeof(u16));
    u16*   F16B   = (u16*)alloc((size_t)NP * FH * sizeof(u16));
    uint4* BF     = (uint4*)alloc((size_t)6 * 4096 * sizeof(uint4));  // 6 x 64KB
    (void)ws_size;

    // ---- prep ----
    prep_x<<<(N * 32 + 255) / 256, 256, 0, stream>>>(x, hPa, F16A, N * 32);
    prep_w<<<dim3(8, 6), 64, 0, stream>>>(W1l, W1r, W2l, W2r, W3l, W3r, BF);

    // ---- CSR build ----
    hipMemsetAsync(cnt, 0, (size_t)2 * N * sizeof(int), stream);
    hist_kernel<<<(E + 255) / 256, 256, 0, stream>>>(dst, cnt, E);
    scanA_kernel<<<NB, 256, 0, stream>>>(cnt, bsum, N);
    scanB_kernel<<<1, 64, 0, stream>>>(bsum, boff, rp, NB, N);
    scanC_kernel<<<NB, 256, 0, stream>>>(cnt, boff, rp, dinv, N);
    scatter_kernel<<<(E + 255) / 256, 256, 0, stream>>>(src, dst, rp, cursor, esrc, E);
    graph_bounds_kernel<<<(N + 255) / 256, 256, 0, stream>>>(batch, gstart, N, G);

    const int agg_grid = (N + 15) / 16;

    // ---- layer 1 ----
    agg_kernel<<<agg_grid, 256, 0, stream>>>(F16A, rp, esrc, dinv, aggP, N);
    mfma_gemm<<<GB, 256, 0, stream>>>(aggP, hPa, BF + 0 * 4096, BF + 1 * 4096, b1, hPb, F16B, 1);
    // ---- layer 2 ----
    agg_kernel<<<agg_grid, 256, 0, stream>>>(F16B, rp, esrc, dinv, aggP, N);
    mfma_gemm<<<GB, 256, 0, stream>>>(aggP, hPb, BF + 2 * 4096, BF + 3 * 4096, b2, hPa, F16A, 1);
    // ---- layer 3 ----
    agg_kernel<<<agg_grid, 256, 0, stream>>>(F16A, rp, esrc, dinv, aggP, N);
    mfma_gemm<<<GB, 256, 0, stream>>>(aggP, hPa, BF + 4 * 4096, BF + 5 * 4096, b3, hPb, (u16*)nullptr, 0);

    // ---- fused pool + head ----
    pool_final<<<G, FH, 0, stream>>>(hPb, gstart, Wlin, blin, out);
}

// Round 7
// 361.157 us; speedup vs baseline: 1.1369x; 1.1369x over previous
//
#include <hip/hip_runtime.h>
#include <hip/hip_bf16.h>
#include <hip/hip_fp16.h>

// GraphSAGE 3-layer + pool + linear.
// R7: pool_final re-parallelized: 8 node-ways x 32 lanes x uint4 per graph,
// LDS tree reduction, then 256-thread GEMV. (R6's 128-thread serial pool was
// latency-bound at 76 us.) GEMM: LDS-staged B tables (R6). agg: fp16 mirror
// gathers (R5). Split-bf16 GEMM: C = Ahi*Bhi + Ahi*Blo + Alo*Bhi.

#define FH 128
#define OUTD 256
#define SCHUNK 2048

typedef unsigned int u32;
typedef unsigned short u16;
typedef __attribute__((ext_vector_type(8))) short bf8frag;
typedef __attribute__((ext_vector_type(4))) float f4frag;

__device__ inline u32 pack_bf16pair(float v) {
    u32 b = __float_as_uint(v);
    u32 hb = (b + 0x7FFFu + ((b >> 16) & 1u)) & 0xFFFF0000u;
    float rem = v - __uint_as_float(hb);
    u32 rb = __float_as_uint(rem);
    u32 lb = ((rb + 0x7FFFu + ((rb >> 16) & 1u)) >> 16) & 0xFFFFu;
    return hb | lb;
}
__device__ inline float unpack_f(u32 u) {
    return __uint_as_float(u & 0xFFFF0000u) + __uint_as_float(u << 16);
}

// ---------------------------------------------------------------- histogram
__global__ void hist_kernel(const int* __restrict__ dst, int* __restrict__ cnt, int E) {
    int e = blockIdx.x * 256 + threadIdx.x;
    if (e < E) atomicAdd(&cnt[dst[e]], 1);
}

// ---------------------------------------------- scan pass A: per-block sums
__global__ void scanA_kernel(const int* __restrict__ cnt, int* __restrict__ bsum, int n) {
    __shared__ int ws[4];
    int b = blockIdx.x, t = threadIdx.x;
    int base = b * SCHUNK + t * 8;
    int s = 0;
    #pragma unroll
    for (int k = 0; k < 8; ++k) {
        int i = base + k;
        s += (i < n) ? cnt[i] : 0;
    }
    #pragma unroll
    for (int off = 32; off >= 1; off >>= 1) s += __shfl_xor(s, off, 64);
    int w = t >> 6, lane = t & 63;
    if (lane == 0) ws[w] = s;
    __syncthreads();
    if (t == 0) bsum[b] = ws[0] + ws[1] + ws[2] + ws[3];
}

// ------------------------------- scan pass B: scan block sums (1 wave)
__global__ void scanB_kernel(const int* __restrict__ bsum, int* __restrict__ boff,
                             int* __restrict__ rp, int B, int n) {
    int t = threadIdx.x;  // 64 threads
    int v = (t < B) ? bsum[t] : 0;
    int x = v;
    #pragma unroll
    for (int off = 1; off < 64; off <<= 1) {
        int y = __shfl_up(x, off, 64);
        if (t >= off) x += y;
    }
    if (t < B) boff[t] = x - v;
    if (t == 63) rp[n] = x;
}

// --------------------------- scan pass C: full exclusive scan + emit rp/dinv
__global__ void scanC_kernel(const int* __restrict__ cnt, const int* __restrict__ boff,
                             int* __restrict__ rp, float* __restrict__ dinv, int n) {
    __shared__ int ws[4];
    int b = blockIdx.x, t = threadIdx.x;
    int base = b * SCHUNK + t * 8;
    int v[8];
    int ts = 0;
    #pragma unroll
    for (int k = 0; k < 8; ++k) {
        int i = base + k;
        v[k] = (i < n) ? cnt[i] : 0;
        ts += v[k];
    }
    int w = t >> 6, lane = t & 63;
    int x = ts;
    #pragma unroll
    for (int off = 1; off < 64; off <<= 1) {
        int y = __shfl_up(x, off, 64);
        if (lane >= off) x += y;
    }
    if (lane == 63) ws[w] = x;
    __syncthreads();
    int woff = 0;
    #pragma unroll
    for (int q = 0; q < 4; ++q) woff += (q < w) ? ws[q] : 0;
    int run = boff[b] + woff + (x - ts);
    #pragma unroll
    for (int k = 0; k < 8; ++k) {
        int i = base + k;
        if (i < n) {
            rp[i] = run;
            dinv[i] = 1.0f / (float)max(v[k], 1);
        }
        run += v[k];
    }
}

// --------------------------------------------------------- CSR edge scatter
__global__ void scatter_kernel(const int* __restrict__ src, const int* __restrict__ dst,
                               const int* __restrict__ rp, int* __restrict__ cursor,
                               int* __restrict__ esrc, int E) {
    int e = blockIdx.x * 256 + threadIdx.x;
    if (e < E) {
        int d = dst[e];
        int pos = rp[d] + atomicAdd(&cursor[d], 1);
        esrc[pos] = src[e];
    }
}

// ------------------------------------------------------- graph range bounds
__global__ void graph_bounds_kernel(const int* __restrict__ batch, int* __restrict__ gstart,
                                    int n, int g) {
    int i = blockIdx.x * 256 + threadIdx.x;
    if (i >= n) return;
    int b = batch[i];
    int pb = (i == 0) ? -1 : batch[i - 1];
    for (int q = pb + 1; q <= b; ++q) gstart[q] = i;
    if (i == n - 1) {
        for (int q = b + 1; q <= g; ++q) gstart[q] = n;
    }
}

// --------------------------------- prep: x -> packed bf16-pair + fp16 mirror
__global__ void prep_x(const float* __restrict__ x, u32* __restrict__ hP,
                       u16* __restrict__ x16, int n4) {
    int id = blockIdx.x * 256 + threadIdx.x;
    if (id >= n4) return;
    float4 v = *(const float4*)(x + (size_t)id * 4);
    uint4 o = {pack_bf16pair(v.x), pack_bf16pair(v.y), pack_bf16pair(v.z), pack_bf16pair(v.w)};
    *(uint4*)(hP + (size_t)id * 4) = o;
    __half h0 = __float2half(v.x), h1 = __float2half(v.y);
    __half h2 = __float2half(v.z), h3 = __float2half(v.w);
    ushort4 s;
    s.x = *(u16*)&h0; s.y = *(u16*)&h1; s.z = *(u16*)&h2; s.w = *(u16*)&h3;
    *(ushort4*)(x16 + (size_t)id * 4) = s;
}

// --------------------- prep: weights -> B fragments in MFMA operand order
// Per array: Bf[(ks*8 + ot)*64 + lane], lane l holds
// W[out=ot*16+(l&15)][k = (ks&3)*32 + (l>>4)*8 + i], i=0..7.
// ks 0-3: hi part, ks 4-7: lo part.
__global__ void prep_w(const float* __restrict__ W0, const float* __restrict__ W1,
                       const float* __restrict__ W2, const float* __restrict__ W3,
                       const float* __restrict__ W4, const float* __restrict__ W5,
                       uint4* __restrict__ Bf) {
    const float* Ws[6] = {W0, W1, W2, W3, W4, W5};
    int ks = blockIdx.x;      // 0..7
    int arr = blockIdx.y;     // 0..5
    int l = threadIdx.x;      // 0..63
    const float* W = Ws[arr];
    bool use_lo = (ks >= 4);
    int kb = (ks & 3) * 32 + (l >> 4) * 8;
    uint4* out = Bf + (size_t)arr * 4096;
    #pragma unroll
    for (int ot = 0; ot < 8; ++ot) {
        int o = ot * 16 + (l & 15);
        u32 h[8];
        #pragma unroll
        for (int i = 0; i < 8; ++i) {
            float v = W[o * 128 + kb + i];
            u32 b = __float_as_uint(v);
            u32 hb = (b + 0x7FFFu + ((b >> 16) & 1u)) & 0xFFFF0000u;
            if (use_lo) {
                float rem = v - __uint_as_float(hb);
                u32 rb = __float_as_uint(rem);
                h[i] = ((rb + 0x7FFFu + ((rb >> 16) & 1u)) >> 16) & 0xFFFFu;
            } else {
                h[i] = hb >> 16;
            }
        }
        uint4 u;
        u.x = h[0] | (h[1] << 16);
        u.y = h[2] | (h[3] << 16);
        u.z = h[4] | (h[5] << 16);
        u.w = h[6] | (h[7] << 16);
        out[(ks * 8 + ot) * 64 + l] = u;
    }
}

// --------------------------------------------------- mean aggregation (CSR)
// 16 lanes per node; lane covers 8 fp16 features (uint4 = 16B); x4 edge unroll.
__device__ inline void add8(float* a, uint4 u) {
    float2 f0 = __half22float2(*(__half2*)&u.x);
    float2 f1 = __half22float2(*(__half2*)&u.y);
    float2 f2 = __half22float2(*(__half2*)&u.z);
    float2 f3 = __half22float2(*(__half2*)&u.w);
    a[0] += f0.x; a[1] += f0.y; a[2] += f1.x; a[3] += f1.y;
    a[4] += f2.x; a[5] += f2.y; a[6] += f3.x; a[7] += f3.y;
}

__global__ void agg_kernel(const u16* __restrict__ h16,
                           const int* __restrict__ rp, const int* __restrict__ esrc,
                           const float* __restrict__ dinv,
                           u32* __restrict__ aggP, int n_nodes) {
    int node = blockIdx.x * 16 + (threadIdx.x >> 4);
    if (node >= n_nodes) return;
    int lane = threadIdx.x & 15;
    int f = lane * 8;
    int s0 = rp[node], s1 = rp[node + 1];
    float a0[8] = {0, 0, 0, 0, 0, 0, 0, 0};
    float a1[8] = {0, 0, 0, 0, 0, 0, 0, 0};
    float a2[8] = {0, 0, 0, 0, 0, 0, 0, 0};
    float a3[8] = {0, 0, 0, 0, 0, 0, 0, 0};
    int j = s0;
    for (; j + 4 <= s1; j += 4) {
        int i0 = esrc[j], i1 = esrc[j + 1], i2 = esrc[j + 2], i3 = esrc[j + 3];
        uint4 u0 = *(const uint4*)(h16 + (size_t)i0 * FH + f);
        uint4 u1 = *(const uint4*)(h16 + (size_t)i1 * FH + f);
        uint4 u2 = *(const uint4*)(h16 + (size_t)i2 * FH + f);
        uint4 u3 = *(const uint4*)(h16 + (size_t)i3 * FH + f);
        add8(a0, u0); add8(a1, u1); add8(a2, u2); add8(a3, u3);
    }
    for (; j < s1; ++j) {
        uint4 u0 = *(const uint4*)(h16 + (size_t)esrc[j] * FH + f);
        add8(a0, u0);
    }
    float di = dinv[node];
    u32 o[8];
    #pragma unroll
    for (int i = 0; i < 8; ++i)
        o[i] = pack_bf16pair((a0[i] + a1[i] + a2[i] + a3[i]) * di);
    uint4 w0 = {o[0], o[1], o[2], o[3]};
    uint4 w1 = {o[4], o[5], o[6], o[7]};
    *(uint4*)(aggP + (size_t)node * FH + f) = w0;
    *(uint4*)(aggP + (size_t)node * FH + f + 4) = w1;
}

// ----------------------------------------------------------- MFMA SAGE GEMM
// 256 threads (4 waves). Tile 192 nodes x 128 outs; wave w: nodes w*48..w*48+47.
// Per source: stage full B table (hi+lo, 64 KB) into LDS cooperatively, one
// barrier, then K-loop with ds_read_b128 B-frags + global A-frags.
__global__ __launch_bounds__(256, 2)
void mfma_gemm(const u32* __restrict__ A1, const u32* __restrict__ A2,
               const uint4* __restrict__ Bf1, const uint4* __restrict__ Bf2,
               const float* __restrict__ bias, u32* __restrict__ outP,
               u16* __restrict__ out16, int do_relu) {
    __shared__ uint4 Bl[4096];  // 64 KB: [ks 0..7][ot 0..7][lane 0..63]
    int tid = threadIdx.x;
    int l = tid & 63;
    int wv = tid >> 6;
    int bn0 = blockIdx.x * 192 + wv * 48;
    int m = l & 15, q = l >> 4;  // q in 0..3

    f4frag acc[3][8];
    #pragma unroll
    for (int i = 0; i < 3; ++i)
        #pragma unroll
        for (int o = 0; o < 8; ++o)
            acc[i][o] = (f4frag){0.f, 0.f, 0.f, 0.f};

    #pragma unroll
    for (int p = 0; p < 2; ++p) {
        const u32* P = p ? A2 : A1;
        const uint4* Bf = p ? Bf2 : Bf1;

        // ---- stage B table for this source ----
        __syncthreads();   // all waves done with previous source's B
        #pragma unroll
        for (int u = 0; u < 16; ++u)
            Bl[u * 256 + tid] = Bf[u * 256 + tid];
        __syncthreads();

        #pragma unroll
        for (int s = 0; s < 4; ++s) {
            // ---- A frags for this k-slice (global, line-tiled) ----
            bf8frag Ahi[3], Alo[3];
            #pragma unroll
            for (int nt = 0; nt < 3; ++nt) {
                const u32* ap = P + (size_t)(bn0 + nt * 16 + m) * FH + q * 8 + s * 32;
                uint4 p0 = *(const uint4*)(ap);
                uint4 p1 = *(const uint4*)(ap + 4);
                uint4 h, lo;
                h.x = (p0.x >> 16) | (p0.y & 0xFFFF0000u);
                h.y = (p0.z >> 16) | (p0.w & 0xFFFF0000u);
                h.z = (p1.x >> 16) | (p1.y & 0xFFFF0000u);
                h.w = (p1.z >> 16) | (p1.w & 0xFFFF0000u);
                lo.x = (p0.x & 0xFFFFu) | (p0.y << 16);
                lo.y = (p0.z & 0xFFFFu) | (p0.w << 16);
                lo.z = (p1.x & 0xFFFFu) | (p1.y << 16);
                lo.w = (p1.z & 0xFFFFu) | (p1.w << 16);
                Ahi[nt] = *(bf8frag*)&h;
                Alo[nt] = *(bf8frag*)&lo;
            }
            // ---- B frags from LDS (conflict-free b128) ----
            bf8frag Bhi[8], Blo[8];
            #pragma unroll
            for (int ot = 0; ot < 8; ++ot) {
                Bhi[ot] = *(const bf8frag*)&Bl[(size_t)((s)     * 8 + ot) * 64 + l];
                Blo[ot] = *(const bf8frag*)&Bl[(size_t)((s + 4) * 8 + ot) * 64 + l];
            }
            // ---- 72 MFMAs, 24 independent acc chains ----
            #pragma unroll
            for (int ot = 0; ot < 8; ++ot)
                #pragma unroll
                for (int nt = 0; nt < 3; ++nt)
                    acc[nt][ot] = __builtin_amdgcn_mfma_f32_16x16x32_bf16(Ahi[nt], Bhi[ot], acc[nt][ot], 0, 0, 0);
            #pragma unroll
            for (int ot = 0; ot < 8; ++ot)
                #pragma unroll
                for (int nt = 0; nt < 3; ++nt)
                    acc[nt][ot] = __builtin_amdgcn_mfma_f32_16x16x32_bf16(Ahi[nt], Blo[ot], acc[nt][ot], 0, 0, 0);
            #pragma unroll
            for (int ot = 0; ot < 8; ++ot)
                #pragma unroll
                for (int nt = 0; nt < 3; ++nt)
                    acc[nt][ot] = __builtin_amdgcn_mfma_f32_16x16x32_bf16(Alo[nt], Bhi[ot], acc[nt][ot], 0, 0, 0);
        }
    }

    // ---- epilogue: bias (+relu), pack, store (D: col=l&15, row=q*4+r) ----
    float vout[3][4][8];
    #pragma unroll
    for (int nt = 0; nt < 3; ++nt)
        #pragma unroll
        for (int r = 0; r < 4; ++r)
            #pragma unroll
            for (int ot = 0; ot < 8; ++ot) {
                float v = acc[nt][ot][r] + bias[ot * 16 + m];
                if (do_relu) v = fmaxf(v, 0.f);
                vout[nt][r][ot] = v;
            }
    #pragma unroll
    for (int nt = 0; nt < 3; ++nt)
        #pragma unroll
        for (int r = 0; r < 4; ++r) {
            int node = bn0 + nt * 16 + q * 4 + r;
            #pragma unroll
            for (int ot = 0; ot < 8; ++ot)
                outP[(size_t)node * FH + ot * 16 + m] = pack_bf16pair(vout[nt][r][ot]);
        }
    if (out16) {
        #pragma unroll
        for (int nt = 0; nt < 3; ++nt)
            #pragma unroll
            for (int r = 0; r < 4; ++r) {
                int node = bn0 + nt * 16 + q * 4 + r;
                #pragma unroll
                for (int ot = 0; ot < 8; ++ot) {
                    __half h = __float2half(vout[nt][r][ot]);
                    out16[(size_t)node * FH + ot * 16 + m] = *(u16*)&h;
                }
            }
    }
}

// --------------------------------------------- fused pooling + final linear
// 256 threads per graph: 8 node-ways x 32 lanes x uint4 (4 features each);
// LDS tree-reduce the 8 partials, then 256-thread GEMV (1 output each).
__global__ __launch_bounds__(256, 2)
void pool_final(const u32* __restrict__ hP, const int* __restrict__ gstart,
                const float* __restrict__ Wlin, const float* __restrict__ blin,
                float* __restrict__ out) {
    __shared__ float smax[8][FH];
    __shared__ float ssum[8][FH];
    __shared__ float pr[2 * FH];
    int g = blockIdx.x;
    int tid = threadIdx.x;
    int way = tid >> 5;           // 0..7
    int lane = tid & 31;          // 0..31
    int f = lane * 4;             // feature base (4 features via uint4)
    int s = gstart[g], e = gstart[g + 1];

    float mx[4] = {-INFINITY, -INFINITY, -INFINITY, -INFINITY};
    float sm[4] = {0.f, 0.f, 0.f, 0.f};
    for (int n = s + way; n < e; n += 8) {
        uint4 u = *(const uint4*)(hP + (size_t)n * FH + f);
        float v0 = unpack_f(u.x), v1 = unpack_f(u.y);
        float v2 = unpack_f(u.z), v3 = unpack_f(u.w);
        mx[0] = fmaxf(mx[0], v0); sm[0] += v0;
        mx[1] = fmaxf(mx[1], v1); sm[1] += v1;
        mx[2] = fmaxf(mx[2], v2); sm[2] += v2;
        mx[3] = fmaxf(mx[3], v3); sm[3] += v3;
    }
    #pragma unroll
    for (int i = 0; i < 4; ++i) {
        smax[way][f + i] = mx[i];
        ssum[way][f + i] = sm[i];
    }
    __syncthreads();
    int c = e - s;
    if (tid < FH) {
        float m2 = -INFINITY, s2 = 0.f;
        #pragma unroll
        for (int w2 = 0; w2 < 8; ++w2) {
            m2 = fmaxf(m2, smax[w2][tid]);
            s2 += ssum[w2][tid];
        }
        pr[tid] = (c > 0) ? m2 : 0.f;
        pr[FH + tid] = s2 / (float)max(c, 1);
    }
    __syncthreads();
    // GEMV: one output per thread
    int o = tid;
    const float4* wr = (const float4*)(Wlin + (size_t)o * (2 * FH));
    float acc = 0.f;
    #pragma unroll
    for (int j = 0; j < (2 * FH) / 4; ++j) {
        float4 wv = wr[j];
        acc += wv.x * pr[j * 4 + 0] + wv.y * pr[j * 4 + 1] +
               wv.z * pr[j * 4 + 2] + wv.w * pr[j * 4 + 3];
    }
    out[(size_t)g * OUTD + o] = acc + blin[o];
}

extern "C" void kernel_launch(void* const* d_in, const int* in_sizes, int n_in,
                              void* d_out, int out_size, void* d_ws, size_t ws_size,
                              hipStream_t stream) {
    const float* x     = (const float*)d_in[0];
    const int*   ei    = (const int*)d_in[1];
    const int*   batch = (const int*)d_in[2];
    const float* W1l = (const float*)d_in[3];
    const float* b1  = (const float*)d_in[4];
    const float* W1r = (const float*)d_in[5];
    const float* W2l = (const float*)d_in[6];
    const float* b2  = (const float*)d_in[7];
    const float* W2r = (const float*)d_in[8];
    const float* W3l = (const float*)d_in[9];
    const float* b3  = (const float*)d_in[10];
    const float* W3r = (const float*)d_in[11];
    const float* Wlin = (const float*)d_in[12];
    const float* blin = (const float*)d_in[13];
    float* out = (float*)d_out;

    const int E = in_sizes[1] / 2;
    const int N = in_sizes[2];
    const int G = out_size / OUTD;
    const int* src = ei;
    const int* dst = ei + E;
    const int NB = (N + SCHUNK - 1) / SCHUNK;
    const int GB = (N + 191) / 192;   // gemm blocks (192-node tiles)
    const int NP = GB * 192;          // padded node count

    // ---- workspace carve-up ----
    char* w = (char*)d_ws;
    auto alloc = [&](size_t bytes) {
        void* p = (void*)w;
        w += (bytes + 255) & ~(size_t)255;
        return p;
    };
    int*   cnt    = (int*)alloc((size_t)2 * N * sizeof(int));
    int*   cursor = cnt + N;
    int*   rp     = (int*)alloc((size_t)(N + 1) * sizeof(int));
    int*   esrc   = (int*)alloc((size_t)E * sizeof(int));
    int*   gstart = (int*)alloc((size_t)(G + 1) * sizeof(int));
    float* dinv   = (float*)alloc((size_t)N * sizeof(float));
    int*   bsum   = (int*)alloc(64 * sizeof(int));
    int*   boff   = (int*)alloc(64 * sizeof(int));
    u32*   aggP   = (u32*)alloc((size_t)NP * FH * sizeof(u32));
    u32*   hPa    = (u32*)alloc((size_t)NP * FH * sizeof(u32));
    u32*   hPb    = (u32*)alloc((size_t)NP * FH * sizeof(u32));
    u16*   F16A   = (u16*)alloc((size_t)NP * FH * sizeof(u16));
    u16*   F16B   = (u16*)alloc((size_t)NP * FH * sizeof(u16));
    uint4* BF     = (uint4*)alloc((size_t)6 * 4096 * sizeof(uint4));  // 6 x 64KB
    (void)ws_size;

    // ---- prep ----
    prep_x<<<(N * 32 + 255) / 256, 256, 0, stream>>>(x, hPa, F16A, N * 32);
    prep_w<<<dim3(8, 6), 64, 0, stream>>>(W1l, W1r, W2l, W2r, W3l, W3r, BF);

    // ---- CSR build ----
    hipMemsetAsync(cnt, 0, (size_t)2 * N * sizeof(int), stream);
    hist_kernel<<<(E + 255) / 256, 256, 0, stream>>>(dst, cnt, E);
    scanA_kernel<<<NB, 256, 0, stream>>>(cnt, bsum, N);
    scanB_kernel<<<1, 64, 0, stream>>>(bsum, boff, rp, NB, N);
    scanC_kernel<<<NB, 256, 0, stream>>>(cnt, boff, rp, dinv, N);
    scatter_kernel<<<(E + 255) / 256, 256, 0, stream>>>(src, dst, rp, cursor, esrc, E);
    graph_bounds_kernel<<<(N + 255) / 256, 256, 0, stream>>>(batch, gstart, N, G);

    const int agg_grid = (N + 15) / 16;

    // ---- layer 1 ----
    agg_kernel<<<agg_grid, 256, 0, stream>>>(F16A, rp, esrc, dinv, aggP, N);
    mfma_gemm<<<GB, 256, 0, stream>>>(aggP, hPa, BF + 0 * 4096, BF + 1 * 4096, b1, hPb, F16B, 1);
    // ---- layer 2 ----
    agg_kernel<<<agg_grid, 256, 0, stream>>>(F16B, rp, esrc, dinv, aggP, N);
    mfma_gemm<<<GB, 256, 0, stream>>>(aggP, hPb, BF + 2 * 4096, BF + 3 * 4096, b2, hPa, F16A, 1);
    // ---- layer 3 ----
    agg_kernel<<<agg_grid, 256, 0, stream>>>(F16A, rp, esrc, dinv, aggP, N);
    mfma_gemm<<<GB, 256, 0, stream>>>(aggP, hPa, BF + 4 * 4096, BF + 5 * 4096, b3, hPb, (u16*)nullptr, 0);

    // ---- fused pool + head ----
    pool_final<<<G, 256, 0, stream>>>(hPb, gstart, Wlin, blin, out);
}